// Round 4
// baseline (218.225 us; speedup 1.0000x reference)
//
#include <hip/hip_runtime.h>

// NPairDiscriminator: N=8192, D=128, tau=0.5. f32 inputs, f32 scalar output.
// loss = mean_i 0.5*(log d1_i + log d2_i - 4*(n1_i . n2_i))
//   d1_i = s11_i + s12_i - exp(|n1_i|^2/tau),  s11_i = sum_j exp((n1_i.n1_j)/tau), etc.

#define NR 8192
#define DIM 128
#define SCALE_EXP2 2.885390081777927f   // 1/(tau*ln2): exp(x/tau) = exp2(x*SCALE)
#define LOG2E 1.442695040888963f

typedef __attribute__((ext_vector_type(8))) short short8;    // 8 bf16 = 4 VGPRs (MFMA A/B frag)
typedef __attribute__((ext_vector_type(4))) float f32x4;
typedef __attribute__((ext_vector_type(16))) float f32x16;   // 32x32 MFMA C/D frag

// Module-scope scratch. Re-initialized every call -> deterministic.
__device__ unsigned short gH[2][NR * DIM];    // elu(fc1(z)) as bf16
__device__ unsigned short gN[2][NR * DIM];    // normalize(fc2(h)) as bf16 (B side, k_loss)
__device__ unsigned short gNs[2][NR * DIM];   // gN * SCALE_EXP2 as bf16 (A side of k_sim)
__device__ float gS[4][NR];                   // s11, s12, s22, s21 row sums
__device__ float gACC;

__device__ inline float b2f(unsigned short h) {
    union { unsigned int u; float f; } x; x.u = ((unsigned int)h) << 16; return x.f;
}
__device__ inline unsigned short f2b(float f) {   // RNE f32->bf16
    union { float f; unsigned int u; } x; x.f = f;
    return (unsigned short)((x.u + 0x7FFFu + ((x.u >> 16) & 1u)) >> 16);
}
__device__ inline short8 ldf8(const float* __restrict__ p) {   // 8 f32 -> bf16 frag
    f32x4 a = *(const f32x4*)p;
    f32x4 b = *(const f32x4*)(p + 4);
    short8 r;
#pragma unroll
    for (int j = 0; j < 4; ++j) r[j] = (short)f2b(a[j]);
#pragma unroll
    for (int j = 0; j < 4; ++j) r[4 + j] = (short)f2b(b[j]);
    return r;
}
__device__ inline f32x16 zero16() {
    f32x16 z;
#pragma unroll
    for (int i = 0; i < 16; ++i) z[i] = 0.0f;
    return z;
}

__global__ void k_zero() {
    int i = blockIdx.x * blockDim.x + threadIdx.x;
    if (i < 4 * NR) ((float*)gS)[i] = 0.0f;
    if (i == 0) gACC = 0.0f;
}

// ---------- layer 1: H = elu(Z @ W1^T + b1), f32 in, bf16 out ----------
__global__ __launch_bounds__(256) void k_proj1(
        const float* __restrict__ Z1, const float* __restrict__ Z2,
        const float* __restrict__ W1, const float* __restrict__ B1) {
    const float* Z = blockIdx.y ? Z2 : Z1;
    unsigned short* H = gH[blockIdx.y];
    int t = threadIdx.x, w = t >> 6, l = t & 63;
    int lr = l & 31, lh = l >> 5;
    long rbase = (long)blockIdx.x * 256 + w * 64;
    short8 zf[2][8];
#pragma unroll
    for (int s = 0; s < 2; ++s)
#pragma unroll
        for (int kc = 0; kc < 8; ++kc)
            zf[s][kc] = ldf8(Z + (rbase + s * 32 + lr) * DIM + kc * 16 + lh * 8);
#pragma unroll
    for (int tt = 0; tt < 4; ++tt) {
        short8 wf[8];
#pragma unroll
        for (int kc = 0; kc < 8; ++kc)
            wf[kc] = ldf8(W1 + (tt * 32 + lr) * DIM + kc * 16 + lh * 8);
        f32x16 a0 = zero16(), a1 = zero16();
#pragma unroll
        for (int kc = 0; kc < 8; ++kc) {
            a0 = __builtin_amdgcn_mfma_f32_32x32x16_bf16(zf[0][kc], wf[kc], a0, 0, 0, 0);
            a1 = __builtin_amdgcn_mfma_f32_32x32x16_bf16(zf[1][kc], wf[kc], a1, 0, 0, 0);
        }
        float bias = B1[tt * 32 + lr];
#pragma unroll
        for (int s = 0; s < 2; ++s)
#pragma unroll
            for (int r = 0; r < 16; ++r) {
                float v = (s ? a1[r] : a0[r]) + bias;
                if (v <= 0.0f) v = __builtin_amdgcn_exp2f(v * LOG2E) - 1.0f;   // elu
                long row = rbase + s * 32 + (r & 3) + 8 * (r >> 2) + 4 * lh;
                H[row * DIM + tt * 32 + lr] = f2b(v);
            }
    }
}

// ---------- layer 2 + normalize: N = normalize(H @ W2^T + b2); also Ns = N*SCALE ----------
__global__ __launch_bounds__(256) void k_proj2(
        const float* __restrict__ W2, const float* __restrict__ B2) {
    const unsigned short* H = gH[blockIdx.y];
    unsigned short* Nn = gN[blockIdx.y];
    unsigned short* Ns = gNs[blockIdx.y];
    int t = threadIdx.x, w = t >> 6, l = t & 63;
    int lr = l & 31, lh = l >> 5;
    long rbase = (long)blockIdx.x * 128 + w * 32;
    short8 hf[8];
#pragma unroll
    for (int kc = 0; kc < 8; ++kc)
        hf[kc] = *(const short8*)(H + (rbase + lr) * DIM + kc * 16 + lh * 8);
    f32x16 acc[4];
#pragma unroll
    for (int tt = 0; tt < 4; ++tt) {
        short8 wf[8];
#pragma unroll
        for (int kc = 0; kc < 8; ++kc)
            wf[kc] = ldf8(W2 + (tt * 32 + lr) * DIM + kc * 16 + lh * 8);
        f32x16 a = zero16();
#pragma unroll
        for (int kc = 0; kc < 8; ++kc)
            a = __builtin_amdgcn_mfma_f32_32x32x16_bf16(hf[kc], wf[kc], a, 0, 0, 0);
        float bias = B2[tt * 32 + lr];
#pragma unroll
        for (int r = 0; r < 16; ++r) a[r] += bias;
        acc[tt] = a;
    }
    float ss[16];
#pragma unroll
    for (int r = 0; r < 16; ++r)
        ss[r] = acc[0][r] * acc[0][r] + acc[1][r] * acc[1][r]
              + acc[2][r] * acc[2][r] + acc[3][r] * acc[3][r];
#pragma unroll
    for (int r = 0; r < 16; ++r) {
        ss[r] += __shfl_xor(ss[r], 1);  ss[r] += __shfl_xor(ss[r], 2);
        ss[r] += __shfl_xor(ss[r], 4);  ss[r] += __shfl_xor(ss[r], 8);
        ss[r] += __shfl_xor(ss[r], 16);
    }
#pragma unroll
    for (int r = 0; r < 16; ++r) {
        float inv = 1.0f / fmaxf(sqrtf(ss[r]), 1e-12f);
        long row = rbase + (r & 3) + 8 * (r >> 2) + 4 * lh;
#pragma unroll
        for (int tt = 0; tt < 4; ++tt) {
            float v = acc[tt][r] * inv;
            Nn[row * DIM + tt * 32 + lr] = f2b(v);
            Ns[row * DIM + tt * 32 + lr] = f2b(v * SCALE_EXP2);
        }
    }
}

// ---------- fused exp-sim row sums: gS[pair][i] += sum_j exp2(a_i . b_j) ----------
// A is pre-scaled by 1/(tau*ln2) -> exp2 applied RAW to the MFMA accumulator.
// grid (32, 4, 8): x = 256-row q block, y = pair {11,12,22,21}, z = 1024-key slice.
// 1024 blocks -> 4 blocks/CU -> 4 waves/SIMD for latency hiding.
__global__ __launch_bounds__(256, 2) void k_sim() {
    int pair = blockIdx.y;
    const unsigned short* A = gNs[(pair < 2) ? 0 : 1];
    const unsigned short* B = gN[(pair == 0) ? 0 : (pair == 1) ? 1 : (pair == 2) ? 1 : 0];
    float* S = gS[pair];
    int t = threadIdx.x, w = t >> 6, l = t & 63;
    int lr = l & 31, lh = l >> 5;
    long qbase = (long)blockIdx.x * 256 + w * 64;
    short8 qf[2][8];
#pragma unroll
    for (int s = 0; s < 2; ++s)
#pragma unroll
        for (int kc = 0; kc < 8; ++kc)
            qf[s][kc] = *(const short8*)(A + (qbase + s * 32 + lr) * DIM + kc * 16 + lh * 8);
    float rs0[16], rs1[16];
#pragma unroll
    for (int r = 0; r < 16; ++r) { rs0[r] = 0.0f; rs1[r] = 0.0f; }
    long kbase = (long)blockIdx.z * 1024;
    for (int kt = 0; kt < 32; ++kt) {
        const unsigned short* Bp = B + (kbase + kt * 32 + lr) * DIM + lh * 8;
        short8 bfr[8];
#pragma unroll
        for (int kc = 0; kc < 8; ++kc)
            bfr[kc] = *(const short8*)(Bp + kc * 16);
        f32x16 a0 = zero16(), a1 = zero16();
#pragma unroll
        for (int kc = 0; kc < 8; ++kc) {
            a0 = __builtin_amdgcn_mfma_f32_32x32x16_bf16(qf[0][kc], bfr[kc], a0, 0, 0, 0);
            a1 = __builtin_amdgcn_mfma_f32_32x32x16_bf16(qf[1][kc], bfr[kc], a1, 0, 0, 0);
        }
#pragma unroll
        for (int r = 0; r < 16; ++r) {
            rs0[r] += __builtin_amdgcn_exp2f(a0[r]);   // raw v_exp_f32, scale pre-folded
            rs1[r] += __builtin_amdgcn_exp2f(a1[r]);
        }
    }
#pragma unroll
    for (int r = 0; r < 16; ++r) {
        rs0[r] += __shfl_xor(rs0[r], 1);  rs0[r] += __shfl_xor(rs0[r], 2);
        rs0[r] += __shfl_xor(rs0[r], 4);  rs0[r] += __shfl_xor(rs0[r], 8);
        rs0[r] += __shfl_xor(rs0[r], 16);
        rs1[r] += __shfl_xor(rs1[r], 1);  rs1[r] += __shfl_xor(rs1[r], 2);
        rs1[r] += __shfl_xor(rs1[r], 4);  rs1[r] += __shfl_xor(rs1[r], 8);
        rs1[r] += __shfl_xor(rs1[r], 16);
    }
    if (lr == 0) {   // lanes 0 and 32 (lh = 0/1) own 16 rows each per subtile
#pragma unroll
        for (int r = 0; r < 16; ++r) {
            int ro = (r & 3) + 8 * (r >> 2) + 4 * lh;
            atomicAdd(&S[qbase + ro], rs0[r]);
            atomicAdd(&S[qbase + 32 + ro], rs1[r]);
        }
    }
}

// ---------- per-row loss + global mean ----------
__global__ __launch_bounds__(256) void k_loss() {
    int t = threadIdx.x, w = t >> 6, l = t & 63;
    int gw = blockIdx.x * 4 + w;   // 256 waves total
    float lsum = 0.0f;
    for (int row = gw; row < NR; row += 256) {
        unsigned int pa = *(const unsigned int*)(&gN[0][row * DIM + l * 2]);
        unsigned int pb = *(const unsigned int*)(&gN[1][row * DIM + l * 2]);
        float a0 = b2f((unsigned short)(pa & 0xFFFFu)), a1 = b2f((unsigned short)(pa >> 16));
        float b0 = b2f((unsigned short)(pb & 0xFFFFu)), b1 = b2f((unsigned short)(pb >> 16));
        float sd1 = a0 * a0 + a1 * a1;
        float sd2 = b0 * b0 + b1 * b1;
        float cr  = a0 * b0 + a1 * b1;
#pragma unroll
        for (int off = 1; off < 64; off <<= 1) {
            sd1 += __shfl_xor(sd1, off);
            sd2 += __shfl_xor(sd2, off);
            cr  += __shfl_xor(cr,  off);
        }
        float d1 = gS[0][row] + gS[1][row] - __builtin_amdgcn_exp2f(sd1 * SCALE_EXP2);
        float d2 = gS[2][row] + gS[3][row] - __builtin_amdgcn_exp2f(sd2 * SCALE_EXP2);
        float v = logf(d1) + logf(d2) - 4.0f * cr;
        if (l == 0) lsum += v;
    }
    if (l == 0) atomicAdd(&gACC, lsum * (0.5f / 8192.0f));
}

__global__ void k_final(float* __restrict__ out) {
    out[0] = gACC;
}

extern "C" void kernel_launch(void* const* d_in, const int* in_sizes, int n_in,
                              void* d_out, int out_size, void* d_ws, size_t ws_size,
                              hipStream_t stream) {
    const float* z1 = (const float*)d_in[0];
    const float* z2 = (const float*)d_in[1];
    const float* w1 = (const float*)d_in[2];
    const float* b1 = (const float*)d_in[3];
    const float* w2 = (const float*)d_in[4];
    const float* b2 = (const float*)d_in[5];

    k_zero<<<dim3(128), 256, 0, stream>>>();
    k_proj1<<<dim3(32, 2), 256, 0, stream>>>(z1, z2, w1, b1);
    k_proj2<<<dim3(64, 2), 256, 0, stream>>>(w2, b2);
    k_sim<<<dim3(32, 4, 8), 256, 0, stream>>>();
    k_loss<<<dim3(64), 256, 0, stream>>>();
    k_final<<<1, 1, 0, stream>>>((float*)d_out);
}

// Round 5
// 186.053 us; speedup vs baseline: 1.1729x; 1.1729x over previous
//
#include <hip/hip_runtime.h>

// NPairDiscriminator: N=8192, D=128, tau=0.5. f32 inputs, f32 scalar output.
// loss = mean_i 0.5*(log d1_i + log d2_i - 4*(n1_i . n2_i))
//   d1_i = (s11_i + s12_i) - exp(|n1_i|^2/tau) = T[i]      - diag1
//   d2_i = (s22_i + s21_i) - exp(|n2_i|^2/tau) = T[NR+i]   - diag2
// where T[q] = sum over ALL 16384 keys (N1 then N2) of exp((a_q . b_j)/tau).

#define NR 8192
#define DIM 128
#define SCALE_EXP2 2.885390081777927f   // 1/(tau*ln2): exp(x/tau) = exp2(x*SCALE)
#define LOG2E 1.442695040888963f
#define NKT 64                           // 2048 keys per z-slice / 32 per tile

typedef __attribute__((ext_vector_type(8))) short short8;    // 8 bf16 = 4 VGPRs (MFMA A/B frag)
typedef __attribute__((ext_vector_type(4))) float f32x4;
typedef __attribute__((ext_vector_type(16))) float f32x16;   // 32x32 MFMA C/D frag

// Module-scope scratch. Re-initialized every call -> deterministic.
__device__ unsigned short gH[2][NR * DIM];   // elu(fc1(z)) as bf16
__device__ unsigned short gN[2 * NR * DIM];  // [n1; n2] normalized, bf16 (B side)
__device__ unsigned short gNs[2 * NR * DIM]; // gN * SCALE_EXP2, bf16 (A side)
__device__ float gT[2 * NR];                 // merged row sums
__device__ float gACC;

__device__ inline float b2f(unsigned short h) {
    union { unsigned int u; float f; } x; x.u = ((unsigned int)h) << 16; return x.f;
}
__device__ inline unsigned short f2b(float f) {   // RNE f32->bf16
    union { float f; unsigned int u; } x; x.f = f;
    return (unsigned short)((x.u + 0x7FFFu + ((x.u >> 16) & 1u)) >> 16);
}
__device__ inline short8 ldf8(const float* __restrict__ p) {   // 8 f32 -> bf16 frag
    f32x4 a = *(const f32x4*)p;
    f32x4 b = *(const f32x4*)(p + 4);
    short8 r;
#pragma unroll
    for (int j = 0; j < 4; ++j) r[j] = (short)f2b(a[j]);
#pragma unroll
    for (int j = 0; j < 4; ++j) r[4 + j] = (short)f2b(b[j]);
    return r;
}
__device__ inline f32x16 zero16() {
    f32x16 z;
#pragma unroll
    for (int i = 0; i < 16; ++i) z[i] = 0.0f;
    return z;
}

__global__ void k_zero() {
    int i = blockIdx.x * blockDim.x + threadIdx.x;
    if (i < 2 * NR) gT[i] = 0.0f;
    if (i == 0) gACC = 0.0f;
}

// ---------- layer 1: H = elu(Z @ W1^T + b1), f32 in, bf16 out ----------
__global__ __launch_bounds__(256) void k_proj1(
        const float* __restrict__ Z1, const float* __restrict__ Z2,
        const float* __restrict__ W1, const float* __restrict__ B1) {
    const float* Z = blockIdx.y ? Z2 : Z1;
    unsigned short* H = gH[blockIdx.y];
    int t = threadIdx.x, w = t >> 6, l = t & 63;
    int lr = l & 31, lh = l >> 5;
    long rbase = (long)blockIdx.x * 256 + w * 64;
    short8 zf[2][8];
#pragma unroll
    for (int s = 0; s < 2; ++s)
#pragma unroll
        for (int kc = 0; kc < 8; ++kc)
            zf[s][kc] = ldf8(Z + (rbase + s * 32 + lr) * DIM + kc * 16 + lh * 8);
#pragma unroll
    for (int tt = 0; tt < 4; ++tt) {
        short8 wf[8];
#pragma unroll
        for (int kc = 0; kc < 8; ++kc)
            wf[kc] = ldf8(W1 + (tt * 32 + lr) * DIM + kc * 16 + lh * 8);
        f32x16 a0 = zero16(), a1 = zero16();
#pragma unroll
        for (int kc = 0; kc < 8; ++kc) {
            a0 = __builtin_amdgcn_mfma_f32_32x32x16_bf16(zf[0][kc], wf[kc], a0, 0, 0, 0);
            a1 = __builtin_amdgcn_mfma_f32_32x32x16_bf16(zf[1][kc], wf[kc], a1, 0, 0, 0);
        }
        float bias = B1[tt * 32 + lr];
#pragma unroll
        for (int s = 0; s < 2; ++s)
#pragma unroll
            for (int r = 0; r < 16; ++r) {
                float v = (s ? a1[r] : a0[r]) + bias;
                if (v <= 0.0f) v = __builtin_amdgcn_exp2f(v * LOG2E) - 1.0f;   // elu
                long row = rbase + s * 32 + (r & 3) + 8 * (r >> 2) + 4 * lh;
                H[row * DIM + tt * 32 + lr] = f2b(v);
            }
    }
}

// ---------- layer 2 + normalize: N = normalize(H @ W2^T + b2); Ns = N*SCALE ----------
__global__ __launch_bounds__(256) void k_proj2(
        const float* __restrict__ W2, const float* __restrict__ B2) {
    const unsigned short* H = gH[blockIdx.y];
    unsigned short* Nn = gN + (long)blockIdx.y * NR * DIM;
    unsigned short* Ns = gNs + (long)blockIdx.y * NR * DIM;
    int t = threadIdx.x, w = t >> 6, l = t & 63;
    int lr = l & 31, lh = l >> 5;
    long rbase = (long)blockIdx.x * 128 + w * 32;
    short8 hf[8];
#pragma unroll
    for (int kc = 0; kc < 8; ++kc)
        hf[kc] = *(const short8*)(H + (rbase + lr) * DIM + kc * 16 + lh * 8);
    f32x16 acc[4];
#pragma unroll
    for (int tt = 0; tt < 4; ++tt) {
        short8 wf[8];
#pragma unroll
        for (int kc = 0; kc < 8; ++kc)
            wf[kc] = ldf8(W2 + (tt * 32 + lr) * DIM + kc * 16 + lh * 8);
        f32x16 a = zero16();
#pragma unroll
        for (int kc = 0; kc < 8; ++kc)
            a = __builtin_amdgcn_mfma_f32_32x32x16_bf16(hf[kc], wf[kc], a, 0, 0, 0);
        float bias = B2[tt * 32 + lr];
#pragma unroll
        for (int r = 0; r < 16; ++r) a[r] += bias;
        acc[tt] = a;
    }
    float ss[16];
#pragma unroll
    for (int r = 0; r < 16; ++r)
        ss[r] = acc[0][r] * acc[0][r] + acc[1][r] * acc[1][r]
              + acc[2][r] * acc[2][r] + acc[3][r] * acc[3][r];
#pragma unroll
    for (int r = 0; r < 16; ++r) {
        ss[r] += __shfl_xor(ss[r], 1);  ss[r] += __shfl_xor(ss[r], 2);
        ss[r] += __shfl_xor(ss[r], 4);  ss[r] += __shfl_xor(ss[r], 8);
        ss[r] += __shfl_xor(ss[r], 16);
    }
#pragma unroll
    for (int r = 0; r < 16; ++r) {
        float inv = 1.0f / fmaxf(sqrtf(ss[r]), 1e-12f);
        long row = rbase + (r & 3) + 8 * (r >> 2) + 4 * lh;
#pragma unroll
        for (int tt = 0; tt < 4; ++tt) {
            float v = acc[tt][r] * inv;
            Nn[row * DIM + tt * 32 + lr] = f2b(v);
            Ns[row * DIM + tt * 32 + lr] = f2b(v * SCALE_EXP2);
        }
    }
}

// ---------- fused exp-sim row sums over ALL keys: gT[q] += sum_j exp2(a_q . b_j) ----------
// grid (64, 1, 8): x = 256-row q block over [0,16384), z = 2048-key slice.
// 512 blocks = 2/CU. Software-pipelined: B loads issued >=1 tile ahead; exp of
// tile kt interleaves with MFMA of tile kt+1 (trans pipe || MFMA pipe).
__global__ __launch_bounds__(256, 2) void k_sim() {
    int t = threadIdx.x, w = t >> 6, l = t & 63;
    int lr = l & 31, lh = l >> 5;
    long qbase = (long)blockIdx.x * 256 + w * 64;
    short8 qf[2][8];
#pragma unroll
    for (int s = 0; s < 2; ++s)
#pragma unroll
        for (int kc = 0; kc < 8; ++kc)
            qf[s][kc] = *(const short8*)(gNs + (qbase + s * 32 + lr) * DIM + kc * 16 + lh * 8);
    float rs0[16], rs1[16];
#pragma unroll
    for (int r = 0; r < 16; ++r) { rs0[r] = 0.0f; rs1[r] = 0.0f; }
    long kb = (long)blockIdx.z * 2048;

#define LOADB(dst, KT) do {                                                     \
    const unsigned short* _p = gN + (kb + (long)(KT) * 32 + lr) * DIM + lh * 8; \
    _Pragma("unroll")                                                           \
    for (int kc = 0; kc < 8; ++kc) dst[kc] = *(const short8*)(_p + kc * 16);    \
} while (0)

    short8 bA[8], bB[8];
    f32x16 cA0, cA1, cB0, cB1;
    LOADB(bA, 0);
    for (int kt = 0; kt < NKT; kt += 2) {
        LOADB(bB, kt + 1);                      // prefetch odd tile
        cA0 = zero16(); cA1 = zero16();
#pragma unroll
        for (int kc = 0; kc < 8; ++kc) {
            cA0 = __builtin_amdgcn_mfma_f32_32x32x16_bf16(qf[0][kc], bA[kc], cA0, 0, 0, 0);
            cA1 = __builtin_amdgcn_mfma_f32_32x32x16_bf16(qf[1][kc], bA[kc], cA1, 0, 0, 0);
        }
        if (kt + 2 < NKT) LOADB(bA, kt + 2);    // prefetch next even tile
        cB0 = zero16(); cB1 = zero16();
#pragma unroll
        for (int kc = 0; kc < 8; ++kc) {        // independent of cA* exps below
            cB0 = __builtin_amdgcn_mfma_f32_32x32x16_bf16(qf[0][kc], bB[kc], cB0, 0, 0, 0);
            cB1 = __builtin_amdgcn_mfma_f32_32x32x16_bf16(qf[1][kc], bB[kc], cB1, 0, 0, 0);
        }
#pragma unroll
        for (int r = 0; r < 16; ++r) {          // exp(A) overlaps MFMA(B) retire
            rs0[r] += __builtin_amdgcn_exp2f(cA0[r]);
            rs1[r] += __builtin_amdgcn_exp2f(cA1[r]);
        }
#pragma unroll
        for (int r = 0; r < 16; ++r) {
            rs0[r] += __builtin_amdgcn_exp2f(cB0[r]);
            rs1[r] += __builtin_amdgcn_exp2f(cB1[r]);
        }
    }
#undef LOADB

#pragma unroll
    for (int r = 0; r < 16; ++r) {
        rs0[r] += __shfl_xor(rs0[r], 1);  rs0[r] += __shfl_xor(rs0[r], 2);
        rs0[r] += __shfl_xor(rs0[r], 4);  rs0[r] += __shfl_xor(rs0[r], 8);
        rs0[r] += __shfl_xor(rs0[r], 16);
        rs1[r] += __shfl_xor(rs1[r], 1);  rs1[r] += __shfl_xor(rs1[r], 2);
        rs1[r] += __shfl_xor(rs1[r], 4);  rs1[r] += __shfl_xor(rs1[r], 8);
        rs1[r] += __shfl_xor(rs1[r], 16);
    }
    if (lr == 0) {   // lanes 0 and 32 (lh = 0/1) own 16 rows each per subtile
#pragma unroll
        for (int r = 0; r < 16; ++r) {
            int ro = (r & 3) + 8 * (r >> 2) + 4 * lh;
            atomicAdd(&gT[qbase + ro], rs0[r]);
            atomicAdd(&gT[qbase + 32 + ro], rs1[r]);
        }
    }
}

// ---------- per-row loss + global mean ----------
__global__ __launch_bounds__(256) void k_loss() {
    int t = threadIdx.x, w = t >> 6, l = t & 63;
    int gw = blockIdx.x * 4 + w;   // 256 waves total
    float lsum = 0.0f;
    for (int row = gw; row < NR; row += 256) {
        unsigned int pa = *(const unsigned int*)(gN + (long)row * DIM + l * 2);
        unsigned int pb = *(const unsigned int*)(gN + (long)(NR + row) * DIM + l * 2);
        float a0 = b2f((unsigned short)(pa & 0xFFFFu)), a1 = b2f((unsigned short)(pa >> 16));
        float b0 = b2f((unsigned short)(pb & 0xFFFFu)), b1 = b2f((unsigned short)(pb >> 16));
        float sd1 = a0 * a0 + a1 * a1;
        float sd2 = b0 * b0 + b1 * b1;
        float cr  = a0 * b0 + a1 * b1;
#pragma unroll
        for (int off = 1; off < 64; off <<= 1) {
            sd1 += __shfl_xor(sd1, off);
            sd2 += __shfl_xor(sd2, off);
            cr  += __shfl_xor(cr,  off);
        }
        float d1 = gT[row]      - __builtin_amdgcn_exp2f(sd1 * SCALE_EXP2);
        float d2 = gT[NR + row] - __builtin_amdgcn_exp2f(sd2 * SCALE_EXP2);
        float v = logf(d1) + logf(d2) - 4.0f * cr;
        if (l == 0) lsum += v;
    }
    if (l == 0) atomicAdd(&gACC, lsum * (0.5f / 8192.0f));
}

__global__ void k_final(float* __restrict__ out) {
    out[0] = gACC;
}

extern "C" void kernel_launch(void* const* d_in, const int* in_sizes, int n_in,
                              void* d_out, int out_size, void* d_ws, size_t ws_size,
                              hipStream_t stream) {
    const float* z1 = (const float*)d_in[0];
    const float* z2 = (const float*)d_in[1];
    const float* w1 = (const float*)d_in[2];
    const float* b1 = (const float*)d_in[3];
    const float* w2 = (const float*)d_in[4];
    const float* b2 = (const float*)d_in[5];

    k_zero<<<dim3(64), 256, 0, stream>>>();
    k_proj1<<<dim3(32, 2), 256, 0, stream>>>(z1, z2, w1, b1);
    k_proj2<<<dim3(64, 2), 256, 0, stream>>>(w2, b2);
    k_sim<<<dim3(64, 1, 8), 256, 0, stream>>>();
    k_loss<<<dim3(64), 256, 0, stream>>>();
    k_final<<<1, 1, 0, stream>>>((float*)d_out);
}